// Round 7
// baseline (585.065 us; speedup 1.0000x reference)
//
#include <hip/hip_runtime.h>

#define H 1024
#define W 1024
#define NIMG 8
#define CPT 4                   // columns per thread
#define TH 8                    // output rows per wave-tile
#define NBX 4                   // x-quadrants: 64 lanes * 4 cols * 4 = 1024
#define WPB 4                   // waves per block, stacked in y
#define NBY (H / (TH * WPB))    // 32
#define NBLK (NBX * NBY * NIMG) // 1024 blocks = 4 blocks/CU = 16 waves/CU
#define NWAVES (NBLK * WPB)     // 4096
#define EPS 1e-5f

struct RS { float I[CPT], J[CPT], II[CPT], JJ[CPT], IJ[CPT]; };

// 6 edge-guarded float4 loads for one (already-clamped) row. Pure load phase;
// results die within the same loop iteration (NO loop-carried raw registers —
// r1/r3/r6 all spilled to scratch from exactly that).
__device__ __forceinline__ void load6(const float* __restrict__ Ip,
                                      const float* __restrict__ Jp,
                                      int r, int X, bool okL, bool okR,
                                      float4& Il, float4& Ic, float4& Ir,
                                      float4& Jl, float4& Jc, float4& Jr) {
  const float* Irow = Ip + (size_t)r * W;
  const float* Jrow = Jp + (size_t)r * W;
  const float4 z = make_float4(0.f, 0.f, 0.f, 0.f);
  Ic = *reinterpret_cast<const float4*>(Irow + X);
  Jc = *reinterpret_cast<const float4*>(Jrow + X);
  if (okL) {
    Il = *reinterpret_cast<const float4*>(Irow + X - 4);
    Jl = *reinterpret_cast<const float4*>(Jrow + X - 4);
  } else { Il = z; Jl = z; }
  if (okR) {
    Ir = *reinterpret_cast<const float4*>(Irow + X + 4);
    Jr = *reinterpret_cast<const float4*>(Jrow + X + 4);
  } else { Ir = z; Jr = z; }
}

// Horizontal 9-box rowsums for 4 output cols from 12 already-loaded px.
__device__ __forceinline__ void rowsums(const float4& Il, const float4& Ic,
                                        const float4& Ir, const float4& Jl,
                                        const float4& Jc, const float4& Jr,
                                        RS& o) {
  const float a[12] = {Il.x, Il.y, Il.z, Il.w, Ic.x, Ic.y, Ic.z, Ic.w,
                       Ir.x, Ir.y, Ir.z, Ir.w};
  const float b[12] = {Jl.x, Jl.y, Jl.z, Jl.w, Jc.x, Jc.y, Jc.z, Jc.w,
                       Jr.x, Jr.y, Jr.z, Jr.w};
  float sI=0.f, sJ=0.f, sII=0.f, sJJ=0.f, sIJ=0.f;
  #pragma unroll
  for (int k = 0; k < 9; ++k) {
    sI += a[k]; sJ += b[k];
    sII = fmaf(a[k], a[k], sII);
    sJJ = fmaf(b[k], b[k], sJJ);
    sIJ = fmaf(a[k], b[k], sIJ);
  }
  o.I[0]=sI; o.J[0]=sJ; o.II[0]=sII; o.JJ[0]=sJJ; o.IJ[0]=sIJ;
  #pragma unroll
  for (int i = 1; i < CPT; ++i) {
    float an=a[i+8], al=a[i-1], bn=b[i+8], bl=b[i-1];
    sI += an - al;  sJ += bn - bl;
    sII = fmaf(-al, al, fmaf(an, an, sII));
    sJJ = fmaf(-bl, bl, fmaf(bn, bn, sJJ));
    sIJ = fmaf(-al, bl, fmaf(an, bn, sIJ));
    o.I[i]=sI; o.J[i]=sJ; o.II[i]=sII; o.JJ[i]=sJJ; o.IJ[i]=sIJ;
  }
}

// No LDS, no barriers. Each wave walks a 256-col x 8-row tile; per-thread
// 4-col strip with vertical running window sums in registers.
// KEY CHANGE (r7): the two row-applies of each steady iteration are merged
// into ONE flat block — all 12 loads issue up-front (leave-row first, fresh-
// row second), so computing the leave rowsums waits only vmcnt(6) while the
// fresh (far-memory) loads stay in flight under ~250 cy of leave compute.
// Previous form serialized two full load->wait->compute chains per iteration
// (VALUBusy ~40%). Warm-up rows processed in pairs for the same reason.
// Evidence log: TLP 16->32 waves/CU null (r5); L1-traffic/3 null (r4);
// cross-iteration reg pipelines spill (r1/r3/r6) -> everything dies in-iter.
__global__ __launch_bounds__(256, 4)
void ncc_main(const float* __restrict__ I, const float* __restrict__ J,
              float* __restrict__ partial) {
  const int tid  = threadIdx.x;
  const int lane = tid & 63, wv = tid >> 6;
  // XCD-bijective remap (NBLK = 1024 = 8 * 128): XCD k (= bid % 8) processes
  // exactly image k -> halo re-reads stay in one XCD's L2.
  const int bid  = (int)blockIdx.x;
  const int tile = ((bid & 7) << 7) | (bid >> 3);
  const int bx   = tile & (NBX - 1);
  const int rest = tile / NBX;            // [0, 256)
  const int by   = rest & (NBY - 1);
  const int bz   = rest / NBY;            // image index == XCD id
  const int X  = bx * 256 + lane * CPT;
  const int y0 = (by * WPB + wv) * TH;
  const bool okL = (X >= 4);
  const bool okR = (X + 8 <= W);
  const size_t img_off = (size_t)bz * H * W;
  const float* Ip = I + img_off;
  const float* Jp = J + img_off;

  float wI[CPT], wJ[CPT], wII[CPT], wJJ[CPT], wIJ[CPT];
  #pragma unroll
  for (int i = 0; i < CPT; ++i) { wI[i]=wJ[i]=wII[i]=wJJ[i]=wIJ[i]=0.f; }
  float acc = 0.f;
  const float inv81 = 1.0f / 81.0f;

  auto emit = [&]() {
    #pragma unroll
    for (int i = 0; i < CPT; ++i) {
      float cross = fmaf(-(wI[i] * wJ[i]), inv81, wIJ[i]);
      float Iv    = fmaf(-(wI[i] * wI[i]), inv81, wII[i]);
      float Jv    = fmaf(-(wJ[i] * wJ[i]), inv81, wJJ[i]);
      acc = fmaf(cross * cross,
                 __builtin_amdgcn_rcpf(fmaf(Iv, Jv, EPS)), acc);
    }
  };

  // ---- warm-up: rows y0-4 .. y0+3, processed in PAIRS (loads of both rows
  // issue before either compute; second row's latency hides under the first's
  // rowsums). Branchless: clamped row + 0/1 scale.
  #pragma unroll
  for (int k = 0; k < 8; k += 2) {
    const int rA = y0 - 4 + k, rB = rA + 1;      // rB <= y0+3 < H always
    const float sA = (rA >= 0) ? 1.f : 0.f;
    const float sB = (rB >= 0) ? 1.f : 0.f;
    const int rAc = max(rA, 0), rBc = max(rB, 0);
    float4 aIl,aIc,aIr,aJl,aJc,aJr, bIl,bIc,bIr,bJl,bJc,bJr;
    load6(Ip, Jp, rAc, X, okL, okR, aIl,aIc,aIr,aJl,aJc,aJr);
    load6(Ip, Jp, rBc, X, okL, okR, bIl,bIc,bIr,bJl,bJc,bJr);
    RS oA; rowsums(aIl,aIc,aIr,aJl,aJc,aJr, oA);
    RS oB; rowsums(bIl,bIc,bIr,bJl,bJc,bJr, oB);
    #pragma unroll
    for (int i = 0; i < CPT; ++i) {
      wI[i]  = fmaf(sA, oA.I[i],  fmaf(sB, oB.I[i],  wI[i]));
      wJ[i]  = fmaf(sA, oA.J[i],  fmaf(sB, oB.J[i],  wJ[i]));
      wII[i] = fmaf(sA, oA.II[i], fmaf(sB, oB.II[i], wII[i]));
      wJJ[i] = fmaf(sA, oA.JJ[i], fmaf(sB, oB.JJ[i], wJJ[i]));
      wIJ[i] = fmaf(sA, oA.IJ[i], fmaf(sB, oB.IJ[i], wIJ[i]));
    }
  }
  // 9th window row y0+4 (always interior), then first output row
  {
    float4 Il,Ic,Ir,Jl,Jc,Jr;
    load6(Ip, Jp, y0 + 4, X, okL, okR, Il,Ic,Ir,Jl,Jc,Jr);
    RS o; rowsums(Il,Ic,Ir,Jl,Jc,Jr, o);
    #pragma unroll
    for (int i = 0; i < CPT; ++i) {
      wI[i] += o.I[i]; wJ[i] += o.J[i]; wII[i] += o.II[i];
      wJJ[i] += o.JJ[i]; wIJ[i] += o.IJ[i];
    }
  }
  emit();

  // ---- steady state: one merged block per output row.
  // Issue order: leave-row loads (near memory) FIRST, fresh-row loads (far)
  // SECOND -> leave compute waits vmcnt(6) only; fresh latency hides under it.
  #pragma unroll
  for (int k = 0; k < TH - 1; ++k) {
    const int rf = y0 + 5 + k;                   // entering row (may be >= H)
    const int rl = y0 - 4 + k;                   // leaving row (may be < 0)
    const float sF = (rf < H)  ? 1.f : 0.f;
    const float sL = (rl >= 0) ? 1.f : 0.f;
    const int rfc = min(rf, H - 1), rlc = max(rl, 0);
    float4 lIl,lIc,lIr,lJl,lJc,lJr, fIl,fIc,fIr,fJl,fJc,fJr;
    load6(Ip, Jp, rlc, X, okL, okR, lIl,lIc,lIr,lJl,lJc,lJr);  // L1/L2-hot
    load6(Ip, Jp, rfc, X, okL, okR, fIl,fIc,fIr,fJl,fJc,fJr);  // HBM/L3
    RS oL; rowsums(lIl,lIc,lIr,lJl,lJc,lJr, oL);
    RS oF; rowsums(fIl,fIc,fIr,fJl,fJc,fJr, oF);
    #pragma unroll
    for (int i = 0; i < CPT; ++i) {
      wI[i]  = fmaf(sF, oF.I[i],  fmaf(-sL, oL.I[i],  wI[i]));
      wJ[i]  = fmaf(sF, oF.J[i],  fmaf(-sL, oL.J[i],  wJ[i]));
      wII[i] = fmaf(sF, oF.II[i], fmaf(-sL, oL.II[i], wII[i]));
      wJJ[i] = fmaf(sF, oF.JJ[i], fmaf(-sL, oL.JJ[i], wJJ[i]));
      wIJ[i] = fmaf(sF, oF.IJ[i], fmaf(-sL, oL.IJ[i], wIJ[i]));
    }
    emit();
  }

  // wave reduction -> one partial per wave (no LDS, no barrier)
  #pragma unroll
  for (int off = 32; off > 0; off >>= 1)
    acc += __shfl_down(acc, off, 64);
  if (lane == 0)
    partial[tile * WPB + wv] = acc;
}

__global__ __launch_bounds__(256)
void ncc_reduce(const float* __restrict__ partial, float* __restrict__ out) {
  __shared__ float red[4];
  const int tid = threadIdx.x;
  const float4* p4 = reinterpret_cast<const float4*>(partial);
  float s = 0.f;
  #pragma unroll
  for (int i = tid; i < NWAVES / 4; i += 256) {
    float4 v = p4[i];
    s += (v.x + v.y) + (v.z + v.w);
  }
  #pragma unroll
  for (int off = 32; off > 0; off >>= 1)
    s += __shfl_down(s, off, 64);
  if ((tid & 63) == 0) red[tid >> 6] = s;
  __syncthreads();
  if (tid == 0)
    out[0] = (red[0] + red[1] + red[2] + red[3]) *
             (1.0f / (float)((size_t)NIMG * H * W));
}

extern "C" void kernel_launch(void* const* d_in, const int* in_sizes, int n_in,
                              void* d_out, int out_size, void* d_ws, size_t ws_size,
                              hipStream_t stream) {
  const float* I = (const float*)d_in[0];
  const float* J = (const float*)d_in[1];
  float* out     = (float*)d_out;
  float* partial = (float*)d_ws;            // 4096 * 4 B = 16 KB

  hipLaunchKernelGGL(ncc_main, dim3(NBLK), dim3(256), 0, stream, I, J, partial);
  hipLaunchKernelGGL(ncc_reduce, dim3(1), dim3(256), 0, stream, partial, out);
}

// Round 8
// 110.894 us; speedup vs baseline: 5.2759x; 5.2759x over previous
//
#include <hip/hip_runtime.h>

#define H 1024
#define W 1024
#define NIMG 8
#define CPT 4                   // columns per thread
#define TH 8                    // output rows per wave-tile
#define NBX 4                   // x-quadrants: 64 lanes * 4 cols * 4 = 1024
#define WPB 4                   // waves per block, stacked in y
#define NBY (H / (TH * WPB))    // 32
#define NBLK (NBX * NBY * NIMG) // 1024 blocks = 4 blocks/CU = 16 waves/CU
#define NWAVES (NBLK * WPB)     // 4096
#define EPS 1e-5f

// 6 edge-guarded float4 loads for one (already-clamped) row. Results die
// within the same iteration (no loop-carried raw registers — r1/r6 spills).
__device__ __forceinline__ void load6(const float* __restrict__ Ip,
                                      const float* __restrict__ Jp,
                                      int r, int X, bool okL, bool okR,
                                      float4& Il, float4& Ic, float4& Ir,
                                      float4& Jl, float4& Jc, float4& Jr) {
  const float* Irow = Ip + (size_t)r * W;
  const float* Jrow = Jp + (size_t)r * W;
  const float4 z = make_float4(0.f, 0.f, 0.f, 0.f);
  Ic = *reinterpret_cast<const float4*>(Irow + X);
  Jc = *reinterpret_cast<const float4*>(Jrow + X);
  if (okL) {
    Il = *reinterpret_cast<const float4*>(Irow + X - 4);
    Jl = *reinterpret_cast<const float4*>(Jrow + X - 4);
  } else { Il = z; Jl = z; }
  if (okR) {
    Ir = *reinterpret_cast<const float4*>(Irow + X + 4);
    Jr = *reinterpret_cast<const float4*>(Jrow + X + 4);
  } else { Ir = z; Jr = z; }
}

// Horizontal 9-box rowsums for 4 output cols, window update FUSED (scaled
// accumulate directly into w*) — NO materialized rowsum struct. r7's spill
// was exactly the two live RS structs (40 regs) on top of 48 px regs.
__device__ __forceinline__ void rs_apply(
    const float4& Il, const float4& Ic, const float4& Ir,
    const float4& Jl, const float4& Jc, const float4& Jr, float scale,
    float wI[CPT], float wJ[CPT], float wII[CPT], float wJJ[CPT],
    float wIJ[CPT])
{
  const float a[12] = {Il.x, Il.y, Il.z, Il.w, Ic.x, Ic.y, Ic.z, Ic.w,
                       Ir.x, Ir.y, Ir.z, Ir.w};
  const float b[12] = {Jl.x, Jl.y, Jl.z, Jl.w, Jc.x, Jc.y, Jc.z, Jc.w,
                       Jr.x, Jr.y, Jr.z, Jr.w};
  float sI=0.f, sJ=0.f, sII=0.f, sJJ=0.f, sIJ=0.f;
  #pragma unroll
  for (int k = 0; k < 9; ++k) {
    sI += a[k]; sJ += b[k];
    sII = fmaf(a[k], a[k], sII);
    sJJ = fmaf(b[k], b[k], sJJ);
    sIJ = fmaf(a[k], b[k], sIJ);
  }
  wI[0]  = fmaf(scale, sI,  wI[0]);
  wJ[0]  = fmaf(scale, sJ,  wJ[0]);
  wII[0] = fmaf(scale, sII, wII[0]);
  wJJ[0] = fmaf(scale, sJJ, wJJ[0]);
  wIJ[0] = fmaf(scale, sIJ, wIJ[0]);
  #pragma unroll
  for (int i = 1; i < CPT; ++i) {
    float an=a[i+8], al=a[i-1], bn=b[i+8], bl=b[i-1];
    sI += an - al;  sJ += bn - bl;
    sII = fmaf(-al, al, fmaf(an, an, sII));
    sJJ = fmaf(-bl, bl, fmaf(bn, bn, sJJ));
    sIJ = fmaf(-al, bl, fmaf(an, bn, sIJ));
    wI[i]  = fmaf(scale, sI,  wI[i]);
    wJ[i]  = fmaf(scale, sJ,  wJ[i]);
    wII[i] = fmaf(scale, sII, wII[i]);
    wJJ[i] = fmaf(scale, sJJ, wJJ[i]);
    wIJ[i] = fmaf(scale, sIJ, wIJ[i]);
  }
}

// No LDS, no barriers. Each wave walks a 256-col x 8-row tile; per-thread
// 4-col strip with vertical running window sums in registers.
// Two-rows-per-block schedule: all 12 float4 loads of an iteration issue
// up-front (near-memory row first, far-memory row second), so the first
// compute waits only vmcnt(6) while the second row's loads stay in flight
// under ~250 cy of compute. Liveness budget: 48 px + 20 window + 5 rowsum
// + ~10 addr ~= 85 regs < 128 cap -> no spill (r7 failed at 138 from RS).
// Evidence: TLP 16->32 waves null (r5); L1 traffic/3 null (r4); loop-carried
// reg pipelines spill (r1/r6); RS-materialized merge spills (r7).
__global__ __launch_bounds__(256, 4)
void ncc_main(const float* __restrict__ I, const float* __restrict__ J,
              float* __restrict__ partial) {
  const int tid  = threadIdx.x;
  const int lane = tid & 63, wv = tid >> 6;
  // XCD-bijective remap (NBLK = 1024 = 8 * 128): XCD k (= bid % 8) processes
  // exactly image k -> halo re-reads stay in one XCD's L2.
  const int bid  = (int)blockIdx.x;
  const int tile = ((bid & 7) << 7) | (bid >> 3);
  const int bx   = tile & (NBX - 1);
  const int rest = tile / NBX;            // [0, 256)
  const int by   = rest & (NBY - 1);
  const int bz   = rest / NBY;            // image index == XCD id
  const int X  = bx * 256 + lane * CPT;
  const int y0 = (by * WPB + wv) * TH;
  const bool okL = (X >= 4);
  const bool okR = (X + 8 <= W);
  const size_t img_off = (size_t)bz * H * W;
  const float* Ip = I + img_off;
  const float* Jp = J + img_off;

  float wI[CPT], wJ[CPT], wII[CPT], wJJ[CPT], wIJ[CPT];
  #pragma unroll
  for (int i = 0; i < CPT; ++i) { wI[i]=wJ[i]=wII[i]=wJJ[i]=wIJ[i]=0.f; }
  float acc = 0.f;
  const float inv81 = 1.0f / 81.0f;

  auto emit = [&]() {
    #pragma unroll
    for (int i = 0; i < CPT; ++i) {
      float cross = fmaf(-(wI[i] * wJ[i]), inv81, wIJ[i]);
      float Iv    = fmaf(-(wI[i] * wI[i]), inv81, wII[i]);
      float Jv    = fmaf(-(wJ[i] * wJ[i]), inv81, wJJ[i]);
      acc = fmaf(cross * cross,
                 __builtin_amdgcn_rcpf(fmaf(Iv, Jv, EPS)), acc);
    }
  };

  // ---- warm-up: rows y0-4 .. y0+3 in pairs (both rows' loads issue before
  // either compute). Branchless: clamped row + 0/1 scale, wave-uniform.
  for (int k = 0; k < 8; k += 2) {
    const int rA = y0 - 4 + k, rB = rA + 1;      // rB <= y0+3 < H always
    const float sA = (rA >= 0) ? 1.f : 0.f;
    const float sB = (rB >= 0) ? 1.f : 0.f;
    const int rAc = max(rA, 0), rBc = max(rB, 0);
    float4 aIl,aIc,aIr,aJl,aJc,aJr, bIl,bIc,bIr,bJl,bJc,bJr;
    load6(Ip, Jp, rAc, X, okL, okR, aIl,aIc,aIr,aJl,aJc,aJr);
    load6(Ip, Jp, rBc, X, okL, okR, bIl,bIc,bIr,bJl,bJc,bJr);
    rs_apply(aIl,aIc,aIr,aJl,aJc,aJr, sA, wI,wJ,wII,wJJ,wIJ);
    rs_apply(bIl,bIc,bIr,bJl,bJc,bJr, sB, wI,wJ,wII,wJJ,wIJ);
  }
  // 9th window row y0+4 (always interior), then first output row
  {
    float4 Il,Ic,Ir,Jl,Jc,Jr;
    load6(Ip, Jp, y0 + 4, X, okL, okR, Il,Ic,Ir,Jl,Jc,Jr);
    rs_apply(Il,Ic,Ir,Jl,Jc,Jr, 1.0f, wI,wJ,wII,wJJ,wIJ);
  }
  emit();

  // ---- steady state: one merged block per output row.
  // Leave-row loads (near memory) FIRST, fresh-row loads (far) SECOND ->
  // leave compute waits vmcnt(6) only; fresh latency hides under it.
  for (int k = 0; k < TH - 1; ++k) {
    const int rf = y0 + 5 + k;                   // entering row (may be >= H)
    const int rl = y0 - 4 + k;                   // leaving row (may be < 0)
    const float sF = (rf < H)  ?  1.f : 0.f;
    const float sL = (rl >= 0) ? -1.f : 0.f;
    const int rfc = min(rf, H - 1), rlc = max(rl, 0);
    float4 lIl,lIc,lIr,lJl,lJc,lJr, fIl,fIc,fIr,fJl,fJc,fJr;
    load6(Ip, Jp, rlc, X, okL, okR, lIl,lIc,lIr,lJl,lJc,lJr);  // L2-hot
    load6(Ip, Jp, rfc, X, okL, okR, fIl,fIc,fIr,fJl,fJc,fJr);  // HBM/L3
    rs_apply(lIl,lIc,lIr,lJl,lJc,lJr, sL, wI,wJ,wII,wJJ,wIJ);
    rs_apply(fIl,fIc,fIr,fJl,fJc,fJr, sF, wI,wJ,wII,wJJ,wIJ);
    emit();
  }

  // wave reduction -> one partial per wave (no LDS, no barrier)
  #pragma unroll
  for (int off = 32; off > 0; off >>= 1)
    acc += __shfl_down(acc, off, 64);
  if (lane == 0)
    partial[tile * WPB + wv] = acc;
}

__global__ __launch_bounds__(256)
void ncc_reduce(const float* __restrict__ partial, float* __restrict__ out) {
  __shared__ float red[4];
  const int tid = threadIdx.x;
  const float4* p4 = reinterpret_cast<const float4*>(partial);
  float s = 0.f;
  #pragma unroll
  for (int i = tid; i < NWAVES / 4; i += 256) {
    float4 v = p4[i];
    s += (v.x + v.y) + (v.z + v.w);
  }
  #pragma unroll
  for (int off = 32; off > 0; off >>= 1)
    s += __shfl_down(s, off, 64);
  if ((tid & 63) == 0) red[tid >> 6] = s;
  __syncthreads();
  if (tid == 0)
    out[0] = (red[0] + red[1] + red[2] + red[3]) *
             (1.0f / (float)((size_t)NIMG * H * W));
}

extern "C" void kernel_launch(void* const* d_in, const int* in_sizes, int n_in,
                              void* d_out, int out_size, void* d_ws, size_t ws_size,
                              hipStream_t stream) {
  const float* I = (const float*)d_in[0];
  const float* J = (const float*)d_in[1];
  float* out     = (float*)d_out;
  float* partial = (float*)d_ws;            // 4096 * 4 B = 16 KB

  hipLaunchKernelGGL(ncc_main, dim3(NBLK), dim3(256), 0, stream, I, J, partial);
  hipLaunchKernelGGL(ncc_reduce, dim3(1), dim3(256), 0, stream, partial, out);
}